// Round 8
// baseline (100.806 us; speedup 1.0000x reference)
//
#include <hip/hip_runtime.h>
#include <math.h>

#ifndef M_PI
#define M_PI 3.14159265358979323846
#endif

#define BATCHES 256
#define S_LEN   131072

// One kernel, fully independent blocks (truncated-warmup linear recurrence).
// Block = 256 threads x 64-sample chunks = 16384-sample segment.
// Warmup: 16 extra chunks (1024 samples); worst pole radius 0.9894 ->
// forgotten-state error ~2e-4 (threshold 2e-2). Verified absmax 0.0039 (r7).
#define TPB   256
#define CCH   64
#define SEGS  8                      // segments per row
#define SEG_SAMPS (TPB * CCH)        // 16384
#define WCH   16                     // warmup chunks
#define PSTR  288                    // padded per-band state stride (chunks)
#define OBSTR 17                     // quarter staging stride (16 samples + pad)
                                     // LDS = 256*17*4 = 17408 B -> 8 blocks/CU (wave-capped)

__device__ __forceinline__ void compute_coeffs(float level_in, float b0[3], float na1[3], float na2[3]) {
    const float FD[3] = {270.0f, 800.0f, 2300.0f};
    const float FN[3] = {500.0f, 1500.0f, 2500.0f};
    const float FB[3] = {730.0f, 2100.0f, 3000.0f};
    float level = fminf(fmaxf(level_in, 0.0f), 1.0f);
    float t_low  = fminf(fmaxf(level * 2.0f, 0.0f), 1.0f);
    float t_high = fminf(fmaxf((level - 0.5f) * 2.0f, 0.0f), 1.0f);
    bool hi = (level >= 0.5f);
    const float W0 = (float)(2.0 * M_PI / 16000.0);
    #pragma unroll
    for (int k = 0; k < 3; ++k) {
        float f, q;
        if (hi) { f = (1.0f - t_high) * FN[k] + t_high * FB[k];
                  q = (1.0f - t_high) * 8.0f  + t_high * 12.0f; }
        else    { f = (1.0f - t_low) * FD[k] + t_low * FN[k];
                  q = (1.0f - t_low) * 5.0f  + t_low * 8.0f; }
        float omega = W0 * f;
        float sn = sinf(omega), cs = cosf(omega);
        float alpha = sn / (2.0f * fmaxf(q, 0.5f));
        float a0 = 1.0f + alpha;
        b0[k]  = alpha / a0;             // b2 == -b0 exactly
        na1[k] = (2.0f * cs) / a0;       // -a1
        na2[k] = -((1.0f - alpha) / a0); // -a2
    }
}

#define STEP3(XT, XTM2, SUMV)                                                    \
    {                                                                            \
        float d = (XT) - (XTM2);                                                 \
        float e0 = fmaf(b0[0], d, na2[0] * y2[0]);                               \
        float e1 = fmaf(b0[1], d, na2[1] * y2[1]);                               \
        float e2 = fmaf(b0[2], d, na2[2] * y2[2]);                               \
        float yy0 = fmaf(na1[0], y1[0], e0);                                     \
        float yy1 = fmaf(na1[1], y1[1], e1);                                     \
        float yy2 = fmaf(na1[2], y1[2], e2);                                     \
        y2[0] = y1[0]; y1[0] = yy0;                                              \
        y2[1] = y1[1]; y1[1] = yy1;                                              \
        y2[2] = y1[2]; y1[2] = yy2;                                              \
        SUMV = (yy0 + yy1 + yy2);                                                \
    }

// 2x2 matrix multiply: R = X * Y
#define MMUL(R00,R01,R10,R11, X00,X01,X10,X11, Y00,Y01,Y10,Y11)                  \
    {                                                                            \
        R00 = X00*Y00 + X01*Y10; R01 = X00*Y01 + X01*Y11;                        \
        R10 = X10*Y00 + X11*Y10; R11 = X10*Y01 + X11*Y11;                        \
    }

__global__ __launch_bounds__(TPB, 8)
void formant_onepass(const float* __restrict__ x, const float* __restrict__ lvl,
                     float* __restrict__ out)
{
    __shared__ float lds[TPB * OBSTR];   // 17408 B; scan uses first 6*288=1728 floats

    const int tid = threadIdx.x;
    const int row = blockIdx.x >> 3;
    const int seg = blockIdx.x & (SEGS - 1);

    float b0[3], na1[3], na2[3];
    compute_coeffs(lvl[row], b0, na1, na2);

    const float* xrow = x + (size_t)row * S_LEN;
    const size_t segBase = (size_t)seg * SEG_SAMPS;
    const float* xc = xrow + segBase + (size_t)tid * CCH;

    float xm1_0 = 0.f, xm2_0 = 0.f;
    if (seg > 0 || tid > 0) { float2 t2 = *(const float2*)(xc - 2); xm2_0 = t2.x; xm1_0 = t2.y; }

    // -------- phase 1a: main-chunk zero-state (stream x, rolling prefetch) --------
    {
        float y1[3] = {0.f,0.f,0.f}, y2[3] = {0.f,0.f,0.f};
        float p1 = xm1_0, p2 = xm2_0, dummy;
        const float4* xv = (const float4*)xc;
        float4 buf[4];
        #pragma unroll
        for (int j = 0; j < 4; ++j) buf[j] = xv[j];
        #pragma unroll
        for (int i = 0; i < 16; ++i) {
            float4 q = buf[i & 3];
            if (i + 4 < 16) buf[i & 3] = xv[i + 4];
            STEP3(q.x, p2, dummy)
            STEP3(q.y, p1, dummy)
            STEP3(q.z, q.x, dummy)
            STEP3(q.w, q.y, dummy)
            p2 = q.z; p1 = q.w;
        }
        (void)dummy;
        lds[0*PSTR + WCH + tid] = y1[0]; lds[1*PSTR + WCH + tid] = y2[0];
        lds[2*PSTR + WCH + tid] = y1[1]; lds[3*PSTR + WCH + tid] = y2[1];
        lds[4*PSTR + WCH + tid] = y1[2]; lds[5*PSTR + WCH + tid] = y2[2];
    }

    // -------- phase 1b: warmup chunks (threads 0..15) --------
    if (tid < WCH) {
        if (seg == 0) {
            #pragma unroll
            for (int e = 0; e < 6; ++e) lds[e*PSTR + tid] = 0.f;   // exact: true zero state
        } else {
            const float* xw = xrow + segBase - (size_t)(WCH * CCH) + (size_t)tid * CCH;
            float2 t2 = *(const float2*)(xw - 2);
            float y1[3] = {0.f,0.f,0.f}, y2[3] = {0.f,0.f,0.f};
            float p2 = t2.x, p1 = t2.y, dummy;
            const float4* xv = (const float4*)xw;
            float4 buf[4];
            #pragma unroll
            for (int j = 0; j < 4; ++j) buf[j] = xv[j];
            #pragma unroll
            for (int i = 0; i < 16; ++i) {
                float4 q = buf[i & 3];
                if (i + 4 < 16) buf[i & 3] = xv[i + 4];
                STEP3(q.x, p2, dummy)
                STEP3(q.y, p1, dummy)
                STEP3(q.z, q.x, dummy)
                STEP3(q.w, q.y, dummy)
                p2 = q.z; p1 = q.w;
            }
            (void)dummy;
            lds[0*PSTR + tid] = y1[0]; lds[1*PSTR + tid] = y2[0];
            lds[2*PSTR + tid] = y1[1]; lds[3*PSTR + tid] = y2[1];
            lds[4*PSTR + tid] = y1[2]; lds[5*PSTR + tid] = y2[2];
        }
    }
    __syncthreads();

    // -------- phase 2: block-local affine scan over 272 chunk states --------
    // lanes 0..15 fold 5 chunks, lanes 16..63 fold 4 (16*5 + 48*4 = 272)
    {
        const int wv = tid >> 6, ln = tid & 63;
        if (wv < 3) {
            const float A1 = na1[wv], A2 = na2[wv];
            float hm1 = 1.f, hm2 = 0.f, hm3 = 0.f;
            for (int i = 0; i < CCH; ++i) {
                float h = fmaf(A1, hm1, A2 * hm2);
                hm3 = hm2; hm2 = hm1; hm1 = h;
            }
            const float H00 = hm1, H01 = A2 * hm2;
            const float H10 = hm2, H11 = A2 * hm3;

            float* z1p = lds + (2*wv) * PSTR;
            float* z2p = lds + (2*wv + 1) * PSTR;

            const int cnt = (ln < 16) ? 5 : 4;
            const int beg = (ln < 16) ? 5 * ln : 80 + 4 * (ln - 16);

            float s1 = 0.f, s2 = 0.f;
            for (int j = 0; j < cnt; ++j) {
                float z1 = z1p[beg + j], z2 = z2p[beg + j];
                float n1 = z1 + H00 * s1 + H01 * s2;
                float n2 = z2 + H10 * s1 + H11 * s2;
                s1 = n1; s2 = n2;
            }
            float B00,B01,B10,B11, C00,C01,C10,C11;
            MMUL(B00,B01,B10,B11, H00,H01,H10,H11, H00,H01,H10,H11)   // H^2
            MMUL(C00,C01,C10,C11, B00,B01,B10,B11, B00,B01,B10,B11)   // H^4
            float A00 = C00, A01 = C01, A10 = C10, A11 = C11;
            if (cnt == 5) {
                float D00,D01,D10,D11;
                MMUL(D00,D01,D10,D11, C00,C01,C10,C11, H00,H01,H10,H11)
                A00 = D00; A01 = D01; A10 = D10; A11 = D11;
            }
            float bb1 = s1, bb2 = s2;
            for (int d = 1; d < 64; d <<= 1) {
                float iA00 = __shfl_up(A00, d), iA01 = __shfl_up(A01, d);
                float iA10 = __shfl_up(A10, d), iA11 = __shfl_up(A11, d);
                float ib1  = __shfl_up(bb1, d), ib2  = __shfl_up(bb2, d);
                if (ln >= d) {
                    float nb1 = A00 * ib1 + A01 * ib2 + bb1;
                    float nb2 = A10 * ib1 + A11 * ib2 + bb2;
                    float n00, n01, n10, n11;
                    MMUL(n00,n01,n10,n11, A00,A01,A10,A11, iA00,iA01,iA10,iA11)
                    A00 = n00; A01 = n01; A10 = n10; A11 = n11;
                    bb1 = nb1; bb2 = nb2;
                }
            }
            float e1 = __shfl_up(bb1, 1), e2 = __shfl_up(bb2, 1);
            if (ln == 0) { e1 = 0.f; e2 = 0.f; }

            // replay: overwrite z with corrected chunk-ENTRY states
            s1 = e1; s2 = e2;
            for (int j = 0; j < cnt; ++j) {
                int w = beg + j;
                float z1 = z1p[w], z2 = z2p[w];
                z1p[w] = s1; z2p[w] = s2;
                float n1 = z1 + H00 * s1 + H01 * s2;
                float n2 = z2 + H10 * s1 + H11 * s2;
                s1 = n1; s2 = n2;
            }
        }
    }
    __syncthreads();

    // -------- phase 3: recurrence with corrected entry; x re-read (L2/L3-hot);
    //          quarter-staged coalesced output --------
    float y1[3], y2[3];
    y1[0] = lds[0*PSTR + WCH + tid]; y2[0] = lds[1*PSTR + WCH + tid];
    y1[1] = lds[2*PSTR + WCH + tid]; y2[1] = lds[3*PSTR + WCH + tid];
    y1[2] = lds[4*PSTR + WCH + tid]; y2[2] = lds[5*PSTR + WCH + tid];
    __syncthreads();   // scan region now reusable as staging

    {
        float p1 = xm1_0, p2 = xm2_0;
        const float is3 = 0.57735026918962576f;   // 1/sqrt(3)
        const float4* xv = (const float4*)xc;
        float* myob = lds + tid * OBSTR;
        float4* obase = (float4*)(out + (size_t)row * S_LEN + segBase);

        #pragma unroll
        for (int qr = 0; qr < 4; ++qr) {          // quarter = 16 samples/thread
            float4 xq[4];
            #pragma unroll
            for (int i = 0; i < 4; ++i) xq[i] = xv[qr * 4 + i];
            #pragma unroll
            for (int i = 0; i < 4; ++i) {
                float4 q = xq[i];
                float4 o;
                STEP3(q.x, p2, o.x)
                STEP3(q.y, p1, o.y)
                STEP3(q.z, q.x, o.z)
                STEP3(q.w, q.y, o.w)
                p2 = q.z; p1 = q.w;
                // scalar LDS writes: bank=(17*tid + 4i+k)%32 -> exactly 2-way (free)
                myob[4*i + 0] = o.x * is3;
                myob[4*i + 1] = o.y * is3;
                myob[4*i + 2] = o.z * is3;
                myob[4*i + 3] = o.w * is3;
            }
            __syncthreads();
            // cooperative store: 1024 float4 (16 KB); 4-lane groups = full 64B lines
            #pragma unroll
            for (int j = 0; j < 4; ++j) {
                int f   = j * TPB + tid;          // float4 index within quarter-block
                int ch  = f >> 2;                 // local chunk (4 float4 per quarter-chunk)
                int off = f & 3;                  // float4 within quarter
                const float* p = lds + ch * OBSTR + off * 4;
                float4 o = { p[0], p[1], p[2], p[3] };
                obase[(size_t)ch * (CCH / 4) + qr * 4 + off] = o;
            }
            __syncthreads();
        }
    }
}

extern "C" void kernel_launch(void* const* d_in, const int* in_sizes, int n_in,
                              void* d_out, int out_size, void* d_ws, size_t ws_size,
                              hipStream_t stream) {
    const float* audio = (const float*)d_in[0];
    const float* level = (const float*)d_in[1];
    float* out = (float*)d_out;
    (void)in_sizes; (void)n_in; (void)d_ws; (void)ws_size; (void)out_size;

    formant_onepass<<<BATCHES * SEGS, TPB, 0, stream>>>(audio, level, out);
}

// Round 9
// 91.086 us; speedup vs baseline: 1.1067x; 1.1067x over previous
//
#include <hip/hip_runtime.h>
#include <math.h>

#ifndef M_PI
#define M_PI 3.14159265358979323846
#endif

#define BATCHES 256
#define S_LEN   131072

// One kernel, fully independent blocks (truncated-warmup linear recurrence).
// Block = 256 threads x 64-sample chunks = 16384-sample segment.
// Warmup: 16 extra chunks (1024 samples); worst pole radius 0.9894 ->
// forgotten-state error ~2e-4 (threshold 2e-2). Verified absmax 0.0039 (r7/r8).
//
// r7->r9 deltas: 8-deep rolling x prefetch (was 4; serial-FMA-gated loop gives
// only ~300cyc slack at depth 4 vs ~900cyc HBM latency), 6 blocks/CU via
// __launch_bounds__(256,6) (r8's (256,8) hit a VGPR cliff: compiler chose 32
// and FETCH blew to 237MB from L3-thrash at 8/CU).
#define TPB   256
#define CCH   64
#define SEGS  8                      // segments per row
#define SEG_SAMPS (TPB * CCH)        // 16384
#define WCH   16                     // warmup chunks
#define PSTR  288                    // padded per-band state stride (chunks)
#define OBSTR 17                     // quarter staging stride (16 samples + pad)
                                     // LDS = 256*17*4 = 17408 B (not the occupancy limiter)

__device__ __forceinline__ void compute_coeffs(float level_in, float b0[3], float na1[3], float na2[3]) {
    const float FD[3] = {270.0f, 800.0f, 2300.0f};
    const float FN[3] = {500.0f, 1500.0f, 2500.0f};
    const float FB[3] = {730.0f, 2100.0f, 3000.0f};
    float level = fminf(fmaxf(level_in, 0.0f), 1.0f);
    float t_low  = fminf(fmaxf(level * 2.0f, 0.0f), 1.0f);
    float t_high = fminf(fmaxf((level - 0.5f) * 2.0f, 0.0f), 1.0f);
    bool hi = (level >= 0.5f);
    const float W0 = (float)(2.0 * M_PI / 16000.0);
    #pragma unroll
    for (int k = 0; k < 3; ++k) {
        float f, q;
        if (hi) { f = (1.0f - t_high) * FN[k] + t_high * FB[k];
                  q = (1.0f - t_high) * 8.0f  + t_high * 12.0f; }
        else    { f = (1.0f - t_low) * FD[k] + t_low * FN[k];
                  q = (1.0f - t_low) * 5.0f  + t_low * 8.0f; }
        float omega = W0 * f;
        float sn = sinf(omega), cs = cosf(omega);
        float alpha = sn / (2.0f * fmaxf(q, 0.5f));
        float a0 = 1.0f + alpha;
        b0[k]  = alpha / a0;             // b2 == -b0 exactly
        na1[k] = (2.0f * cs) / a0;       // -a1
        na2[k] = -((1.0f - alpha) / a0); // -a2
    }
}

#define STEP3(XT, XTM2, SUMV)                                                    \
    {                                                                            \
        float d = (XT) - (XTM2);                                                 \
        float e0 = fmaf(b0[0], d, na2[0] * y2[0]);                               \
        float e1 = fmaf(b0[1], d, na2[1] * y2[1]);                               \
        float e2 = fmaf(b0[2], d, na2[2] * y2[2]);                               \
        float yy0 = fmaf(na1[0], y1[0], e0);                                     \
        float yy1 = fmaf(na1[1], y1[1], e1);                                     \
        float yy2 = fmaf(na1[2], y1[2], e2);                                     \
        y2[0] = y1[0]; y1[0] = yy0;                                              \
        y2[1] = y1[1]; y1[1] = yy1;                                              \
        y2[2] = y1[2]; y1[2] = yy2;                                              \
        SUMV = (yy0 + yy1 + yy2);                                                \
    }

// 2x2 matrix multiply: R = X * Y
#define MMUL(R00,R01,R10,R11, X00,X01,X10,X11, Y00,Y01,Y10,Y11)                  \
    {                                                                            \
        R00 = X00*Y00 + X01*Y10; R01 = X00*Y01 + X01*Y11;                        \
        R10 = X10*Y00 + X11*Y10; R11 = X10*Y01 + X11*Y11;                        \
    }

__global__ __launch_bounds__(TPB, 6)
void formant_onepass(const float* __restrict__ x, const float* __restrict__ lvl,
                     float* __restrict__ out)
{
    __shared__ float lds[TPB * OBSTR];   // 17408 B; scan uses first 6*288=1728 floats

    const int tid = threadIdx.x;
    const int row = blockIdx.x >> 3;
    const int seg = blockIdx.x & (SEGS - 1);

    float b0[3], na1[3], na2[3];
    compute_coeffs(lvl[row], b0, na1, na2);

    const float* xrow = x + (size_t)row * S_LEN;
    const size_t segBase = (size_t)seg * SEG_SAMPS;
    const float* xc = xrow + segBase + (size_t)tid * CCH;

    float xm1_0 = 0.f, xm2_0 = 0.f;
    if (seg > 0 || tid > 0) { float2 t2 = *(const float2*)(xc - 2); xm2_0 = t2.x; xm1_0 = t2.y; }

    // -------- phase 1a: main-chunk zero-state (8-deep rolling prefetch) --------
    {
        float y1[3] = {0.f,0.f,0.f}, y2[3] = {0.f,0.f,0.f};
        float p1 = xm1_0, p2 = xm2_0, dummy;
        const float4* xv = (const float4*)xc;
        float4 buf[8];
        #pragma unroll
        for (int j = 0; j < 8; ++j) buf[j] = xv[j];
        #pragma unroll
        for (int i = 0; i < 16; ++i) {
            float4 q = buf[i & 7];
            if (i + 8 < 16) buf[i & 7] = xv[i + 8];
            STEP3(q.x, p2, dummy)
            STEP3(q.y, p1, dummy)
            STEP3(q.z, q.x, dummy)
            STEP3(q.w, q.y, dummy)
            p2 = q.z; p1 = q.w;
        }
        (void)dummy;
        lds[0*PSTR + WCH + tid] = y1[0]; lds[1*PSTR + WCH + tid] = y2[0];
        lds[2*PSTR + WCH + tid] = y1[1]; lds[3*PSTR + WCH + tid] = y2[1];
        lds[4*PSTR + WCH + tid] = y1[2]; lds[5*PSTR + WCH + tid] = y2[2];
    }

    // -------- phase 1b: warmup chunks (threads 0..15) --------
    if (tid < WCH) {
        if (seg == 0) {
            #pragma unroll
            for (int e = 0; e < 6; ++e) lds[e*PSTR + tid] = 0.f;   // exact: true zero state
        } else {
            const float* xw = xrow + segBase - (size_t)(WCH * CCH) + (size_t)tid * CCH;
            float2 t2 = *(const float2*)(xw - 2);
            float y1[3] = {0.f,0.f,0.f}, y2[3] = {0.f,0.f,0.f};
            float p2 = t2.x, p1 = t2.y, dummy;
            const float4* xv = (const float4*)xw;
            float4 buf[8];
            #pragma unroll
            for (int j = 0; j < 8; ++j) buf[j] = xv[j];
            #pragma unroll
            for (int i = 0; i < 16; ++i) {
                float4 q = buf[i & 7];
                if (i + 8 < 16) buf[i & 7] = xv[i + 8];
                STEP3(q.x, p2, dummy)
                STEP3(q.y, p1, dummy)
                STEP3(q.z, q.x, dummy)
                STEP3(q.w, q.y, dummy)
                p2 = q.z; p1 = q.w;
            }
            (void)dummy;
            lds[0*PSTR + tid] = y1[0]; lds[1*PSTR + tid] = y2[0];
            lds[2*PSTR + tid] = y1[1]; lds[3*PSTR + tid] = y2[1];
            lds[4*PSTR + tid] = y1[2]; lds[5*PSTR + tid] = y2[2];
        }
    }
    __syncthreads();

    // -------- phase 2: block-local affine scan over 272 chunk states --------
    // lanes 0..15 fold 5 chunks, lanes 16..63 fold 4 (16*5 + 48*4 = 272)
    {
        const int wv = tid >> 6, ln = tid & 63;
        if (wv < 3) {
            const float A1 = na1[wv], A2 = na2[wv];
            float hm1 = 1.f, hm2 = 0.f, hm3 = 0.f;
            for (int i = 0; i < CCH; ++i) {
                float h = fmaf(A1, hm1, A2 * hm2);
                hm3 = hm2; hm2 = hm1; hm1 = h;
            }
            const float H00 = hm1, H01 = A2 * hm2;
            const float H10 = hm2, H11 = A2 * hm3;

            float* z1p = lds + (2*wv) * PSTR;
            float* z2p = lds + (2*wv + 1) * PSTR;

            const int cnt = (ln < 16) ? 5 : 4;
            const int beg = (ln < 16) ? 5 * ln : 80 + 4 * (ln - 16);

            float s1 = 0.f, s2 = 0.f;
            for (int j = 0; j < cnt; ++j) {
                float z1 = z1p[beg + j], z2 = z2p[beg + j];
                float n1 = z1 + H00 * s1 + H01 * s2;
                float n2 = z2 + H10 * s1 + H11 * s2;
                s1 = n1; s2 = n2;
            }
            float B00,B01,B10,B11, C00,C01,C10,C11;
            MMUL(B00,B01,B10,B11, H00,H01,H10,H11, H00,H01,H10,H11)   // H^2
            MMUL(C00,C01,C10,C11, B00,B01,B10,B11, B00,B01,B10,B11)   // H^4
            float A00 = C00, A01 = C01, A10 = C10, A11 = C11;
            if (cnt == 5) {
                float D00,D01,D10,D11;
                MMUL(D00,D01,D10,D11, C00,C01,C10,C11, H00,H01,H10,H11)
                A00 = D00; A01 = D01; A10 = D10; A11 = D11;
            }
            float bb1 = s1, bb2 = s2;
            for (int d = 1; d < 64; d <<= 1) {
                float iA00 = __shfl_up(A00, d), iA01 = __shfl_up(A01, d);
                float iA10 = __shfl_up(A10, d), iA11 = __shfl_up(A11, d);
                float ib1  = __shfl_up(bb1, d), ib2  = __shfl_up(bb2, d);
                if (ln >= d) {
                    float nb1 = A00 * ib1 + A01 * ib2 + bb1;
                    float nb2 = A10 * ib1 + A11 * ib2 + bb2;
                    float n00, n01, n10, n11;
                    MMUL(n00,n01,n10,n11, A00,A01,A10,A11, iA00,iA01,iA10,iA11)
                    A00 = n00; A01 = n01; A10 = n10; A11 = n11;
                    bb1 = nb1; bb2 = nb2;
                }
            }
            float e1 = __shfl_up(bb1, 1), e2 = __shfl_up(bb2, 1);
            if (ln == 0) { e1 = 0.f; e2 = 0.f; }

            // replay: overwrite z with corrected chunk-ENTRY states
            s1 = e1; s2 = e2;
            for (int j = 0; j < cnt; ++j) {
                int w = beg + j;
                float z1 = z1p[w], z2 = z2p[w];
                z1p[w] = s1; z2p[w] = s2;
                float n1 = z1 + H00 * s1 + H01 * s2;
                float n2 = z2 + H10 * s1 + H11 * s2;
                s1 = n1; s2 = n2;
            }
        }
    }
    __syncthreads();

    // -------- phase 3: recurrence with corrected entry; x re-read (L2/L3-hot);
    //          quarter-staged coalesced output --------
    float y1[3], y2[3];
    y1[0] = lds[0*PSTR + WCH + tid]; y2[0] = lds[1*PSTR + WCH + tid];
    y1[1] = lds[2*PSTR + WCH + tid]; y2[1] = lds[3*PSTR + WCH + tid];
    y1[2] = lds[4*PSTR + WCH + tid]; y2[2] = lds[5*PSTR + WCH + tid];
    __syncthreads();   // scan region now reusable as staging

    {
        float p1 = xm1_0, p2 = xm2_0;
        const float is3 = 0.57735026918962576f;   // 1/sqrt(3)
        const float4* xv = (const float4*)xc;
        float* myob = lds + tid * OBSTR;
        float4* obase = (float4*)(out + (size_t)row * S_LEN + segBase);

        float4 buf[8];
        #pragma unroll
        for (int j = 0; j < 8; ++j) buf[j] = xv[j];

        #pragma unroll
        for (int qr = 0; qr < 4; ++qr) {          // quarter = 16 samples/thread
            #pragma unroll
            for (int i4 = 0; i4 < 4; ++i4) {
                int i = qr * 4 + i4;
                float4 q = buf[i & 7];
                if (i + 8 < 16) buf[i & 7] = xv[i + 8];
                float4 o;
                STEP3(q.x, p2, o.x)
                STEP3(q.y, p1, o.y)
                STEP3(q.z, q.x, o.z)
                STEP3(q.w, q.y, o.w)
                p2 = q.z; p1 = q.w;
                // scalar LDS writes: bank=(17*tid + 4*i4+k)%32 -> exactly 2-way (free)
                myob[4*i4 + 0] = o.x * is3;
                myob[4*i4 + 1] = o.y * is3;
                myob[4*i4 + 2] = o.z * is3;
                myob[4*i4 + 3] = o.w * is3;
            }
            __syncthreads();
            // cooperative store: 1024 float4 (16 KB); 4-lane groups = full 64B lines
            #pragma unroll
            for (int j = 0; j < 4; ++j) {
                int f   = j * TPB + tid;          // float4 index within quarter-block
                int ch  = f >> 2;                 // local chunk (4 float4 per quarter-chunk)
                int off = f & 3;                  // float4 within quarter
                const float* p = lds + ch * OBSTR + off * 4;
                float4 o = { p[0], p[1], p[2], p[3] };
                obase[(size_t)ch * (CCH / 4) + qr * 4 + off] = o;
            }
            __syncthreads();
        }
    }
}

extern "C" void kernel_launch(void* const* d_in, const int* in_sizes, int n_in,
                              void* d_out, int out_size, void* d_ws, size_t ws_size,
                              hipStream_t stream) {
    const float* audio = (const float*)d_in[0];
    const float* level = (const float*)d_in[1];
    float* out = (float*)d_out;
    (void)in_sizes; (void)n_in; (void)d_ws; (void)ws_size; (void)out_size;

    formant_onepass<<<BATCHES * SEGS, TPB, 0, stream>>>(audio, level, out);
}